// Round 13
// baseline (594.975 us; speedup 1.0000x reference)
//
#include <hip/hip_runtime.h>
#include <hip/hip_bf16.h>

// Problem constants (from reference)
constexpr int NN = 50000;   // nodes
constexpr int EE = 800000;  // edges
constexpr int C  = 128;     // channels (IN == H == 128)
constexpr int KC = 20;      // clusters
constexpr int NB = (NN + 1023) / 1024;   // scan blocks (49)

typedef __attribute__((ext_vector_type(8))) short bf16x8;   // 8 bf16 (4 VGPRs)
typedef __attribute__((ext_vector_type(4))) float f32x4;
typedef __attribute__((ext_vector_type(4))) unsigned int u32x4;
typedef unsigned long long u64;

__device__ inline unsigned short f2bf(float f) {            // RN f32->bf16
    unsigned u = __float_as_uint(f);
    u += 0x7fff + ((u >> 16) & 1);
    return (unsigned short)(u >> 16);
}
__device__ inline float bf2f(unsigned short h) {
    return __uint_as_float(((unsigned)h) << 16);
}

// ---------------------------------------------------------------------------
// Graph preprocessing (int inputs are int32 on device)
// ---------------------------------------------------------------------------

__global__ __launch_bounds__(256) void k_scan1(const unsigned* __restrict__ cnt,
                                               unsigned* __restrict__ bsum) {
    __shared__ unsigned red[256];
    int b = blockIdx.x, t = threadIdx.x;
    int i0 = b * 1024 + t * 4;
    unsigned s = 0;
    #pragma unroll
    for (int j = 0; j < 4; ++j) { int i = i0 + j; s += (i < NN) ? cnt[i] : 0u; }
    red[t] = s; __syncthreads();
    for (int st = 128; st > 0; st >>= 1) { if (t < st) red[t] += red[t + st]; __syncthreads(); }
    if (t == 0) bsum[b] = red[0];
}

__global__ void k_scan2(unsigned* bsum, unsigned* total) {   // 1 block, 64 thr
    int t = threadIdx.x;
    unsigned v = (t < NB) ? bsum[t] : 0u;
    unsigned x = v;
    #pragma unroll
    for (int s = 1; s < 64; s <<= 1) { unsigned u = __shfl_up(x, s, 64); if (t >= s) x += u; }
    if (t < NB) bsum[t] = x - v;     // exclusive block offset
    if (t == 63) *total = x;
}

__global__ __launch_bounds__(256) void k_scan3(const unsigned* __restrict__ cnt,
                                               const unsigned* __restrict__ bsum,
                                               const unsigned* __restrict__ total,
                                               unsigned* __restrict__ off,
                                               unsigned* __restrict__ cursor) {
    __shared__ unsigned wred[4];
    int b = blockIdx.x, t = threadIdx.x, lane = t & 63, wv = t >> 6;
    int i0 = b * 1024 + t * 4;
    unsigned v[4]; unsigned s = 0;
    #pragma unroll
    for (int j = 0; j < 4; ++j) { int i = i0 + j; v[j] = (i < NN) ? cnt[i] : 0u; s += v[j]; }
    unsigned x = s;
    #pragma unroll
    for (int st = 1; st < 64; st <<= 1) { unsigned u = __shfl_up(x, st, 64); if (lane >= st) x += u; }
    if (lane == 63) wred[wv] = x;
    __syncthreads();
    unsigned woff = 0;
    for (int k = 0; k < 4; ++k) if (k < wv) woff += wred[k];
    unsigned excl = bsum[b] + woff + x - s;
    #pragma unroll
    for (int j = 0; j < 4; ++j) {
        int i = i0 + j;
        if (i < NN) { off[i] = excl; cursor[i] = excl; excl += v[j]; }
    }
    if (b == 0 && t == 0) off[NN] = *total;
}

// CSR fill: plain cached loads + cached scatter store (round-7 behavior)
__global__ void k_fill(const int* __restrict__ ei, const float* __restrict__ ew,
                       unsigned* cursor, uint2* __restrict__ em) {
    int e = blockIdx.x * 256 + threadIdx.x;
    if (e >= EE) return;
    int s = ei[e];
    int d = ei[EE + e];
    unsigned p = atomicAdd(&cursor[d], 1u);
    em[p] = make_uint2((unsigned)s, __float_as_uint(ew[e]));
}

// deg[i] = 1 + sum(raw weights of row i); dinv = rsqrt
__global__ void k_dinv_csr(const unsigned* __restrict__ off,
                           const uint2* __restrict__ em, float* __restrict__ dinv) {
    int i = blockIdx.x * 256 + threadIdx.x;
    if (i >= NN) return;
    unsigned p0 = off[i], p1 = off[i + 1];
    float s = 1.0f;                       // self-loop weight
    for (unsigned p = p0; p < p1; ++p) s += __uint_as_float(em[p].y);
    dinv[i] = (s > 0.f) ? rsqrtf(s) : 0.f;
}

// em[p].w *= dinv[src]*dinv[dst]
__global__ void k_scale(const unsigned* __restrict__ off, const float* __restrict__ dinv,
                        uint2* __restrict__ em) {
    int i = blockIdx.x * 256 + threadIdx.x;
    if (i >= NN) return;
    float di = dinv[i];
    unsigned p0 = off[i], p1 = off[i + 1];
    for (unsigned p = p0; p < p1; ++p) {
        uint2 e = em[p];
        em[p].y = __float_as_uint(dinv[e.x] * __uint_as_float(e.y) * di);
    }
}

// ---------------------------------------------------------------------------
// Weight preconversion: 5 mats W[128][128] f32 -> Wt_hi/lo[col][k] bf16 (W^T)
// ---------------------------------------------------------------------------

__global__ void k_wsplit(const float* W0, const float* W1, const float* W2,
                         const float* W3, const float* W4,
                         unsigned short* __restrict__ wt) {
    int m = blockIdx.x >> 6;
    const float* W = (m == 0) ? W0 : (m == 1) ? W1 : (m == 2) ? W2 : (m == 3) ? W3 : W4;
    int idx = (blockIdx.x & 63) * 256 + threadIdx.x;   // 0..16383
    int k = idx >> 7, j = idx & 127;
    float v = W[idx];
    unsigned short h = f2bf(v);
    unsigned short* hi = wt + (size_t)(2 * m) * C * C;
    unsigned short* lo = wt + (size_t)(2 * m + 1) * C * C;
    hi[j * C + k] = h;
    lo[j * C + k] = f2bf(v - bf2f(h));
}

// ---------------------------------------------------------------------------
// k_hist_mm: fused launch. Blocks [0,histBlocks): dst histogram (atomic-bound,
// ~0.3% VALU -> hides the GEMM). Blocks [histBlocks,...): layer-1 GEMM
// G = x @ W1 (f32 A, 3-term hi/lo split) -> row-major bf16 plane.
// ---------------------------------------------------------------------------

__global__ __launch_bounds__(256) void k_hist_mm(const int* __restrict__ ei,
                                                 unsigned* cnt,
                                                 const float* __restrict__ A,
                                                 const unsigned short* __restrict__ Bh,
                                                 const unsigned short* __restrict__ Bl,
                                                 unsigned short* __restrict__ G,
                                                 int histBlocks) {
    int tid = threadIdx.x;
    if (blockIdx.x < histBlocks) {
        int e = blockIdx.x * 256 + tid;
        if (e < EE) atomicAdd(&cnt[__builtin_nontemporal_load(ei + EE + e)], 1u);
        return;
    }
    // ---- mm_f32 part ----
    __shared__ unsigned short Ah[64 * 128];
    __shared__ unsigned short Al[64 * 128];
    int lane = tid & 63;
    int wv   = tid >> 6;
    int row0 = (blockIdx.x - histBlocks) * 64;

    {
        int r  = tid >> 2;                 // 0..63
        int c0 = (tid & 3) * 32;
        int gr = row0 + r;
        bool ok = gr < NN;
        const float* src = A + (size_t)(ok ? gr : 0) * C + c0;
        #pragma unroll
        for (int g = 0; g < 4; ++g) {
            float f[8];
            if (ok) {
                *(float4*)&f[0] = *(const float4*)(src + g * 8);
                *(float4*)&f[4] = *(const float4*)(src + g * 8 + 4);
            } else {
                #pragma unroll
                for (int j = 0; j < 8; ++j) f[j] = 0.f;
            }
            union { unsigned short u[8]; uint4 v; } ph, pl;
            #pragma unroll
            for (int j = 0; j < 8; ++j) {
                unsigned short h = f2bf(f[j]);
                ph.u[j] = h;
                pl.u[j] = f2bf(f[j] - bf2f(h));
            }
            int k = c0 + g * 8;
            int byte = (r * 256 + k * 2) ^ ((r & 7) << 4);
            *(uint4*)((char*)Ah + byte) = ph.v;
            *(uint4*)((char*)Al + byte) = pl.v;
        }
    }

    bf16x8 bh[2][4], bl[2][4];
    #pragma unroll
    for (int cf = 0; cf < 2; ++cf) {
        int col = wv * 32 + cf * 16 + (lane & 15);
        #pragma unroll
        for (int kt = 0; kt < 4; ++kt) {
            int k = kt * 32 + (lane >> 4) * 8;
            bh[cf][kt] = *(const bf16x8*)(Bh + (size_t)col * C + k);
            bl[cf][kt] = *(const bf16x8*)(Bl + (size_t)col * C + k);
        }
    }

    __syncthreads();

    f32x4 zero = {0.f, 0.f, 0.f, 0.f};
    f32x4 acc[4][2];
    #pragma unroll
    for (int rf = 0; rf < 4; ++rf)
        #pragma unroll
        for (int cf = 0; cf < 2; ++cf) acc[rf][cf] = zero;

    #pragma unroll
    for (int rf = 0; rf < 4; ++rf) {
        int row = rf * 16 + (lane & 15);
        #pragma unroll
        for (int kt = 0; kt < 4; ++kt) {
            int k = kt * 32 + (lane >> 4) * 8;
            int byte = (row * 256 + k * 2) ^ ((row & 7) << 4);
            bf16x8 ah = *(const bf16x8*)((const char*)Ah + byte);
            bf16x8 al = *(const bf16x8*)((const char*)Al + byte);
            #pragma unroll
            for (int cf = 0; cf < 2; ++cf) {
                acc[rf][cf] = __builtin_amdgcn_mfma_f32_16x16x32_bf16(ah, bh[cf][kt], acc[rf][cf], 0, 0, 0);
                acc[rf][cf] = __builtin_amdgcn_mfma_f32_16x16x32_bf16(al, bh[cf][kt], acc[rf][cf], 0, 0, 0);
                acc[rf][cf] = __builtin_amdgcn_mfma_f32_16x16x32_bf16(ah, bl[cf][kt], acc[rf][cf], 0, 0, 0);
            }
        }
    }

    #pragma unroll
    for (int cf = 0; cf < 2; ++cf) {
        int col = wv * 32 + cf * 16 + (lane & 15);
        #pragma unroll
        for (int rf = 0; rf < 4; ++rf) {
            #pragma unroll
            for (int q = 0; q < 4; ++q) {
                int row = row0 + rf * 16 + (lane >> 4) * 4 + q;
                if (row < NN) G[(size_t)row * C + col] = f2bf(acc[rf][cf][q]);
            }
        }
    }
}

// ---------------------------------------------------------------------------
// k_mm2: G = A @ W for one or two chains (A bf16 plane exact -> 2-term MFMA).
// grid = nblk (single) or 2*nblk (dual: blockIdx>=nblk -> chain 1).
// ---------------------------------------------------------------------------

__global__ __launch_bounds__(256) void k_mm2(const unsigned short* __restrict__ Ap,
                                             const unsigned short* __restrict__ An,
                                             const unsigned short* __restrict__ Bh,
                                             const unsigned short* __restrict__ Bl,
                                             unsigned short* __restrict__ Gp,
                                             unsigned short* __restrict__ Gn, int nblk) {
    __shared__ unsigned short Ah[64 * 128];
    int tid  = threadIdx.x;
    int lane = tid & 63;
    int wv   = tid >> 6;
    int chain = blockIdx.x >= nblk;
    int blk   = chain ? blockIdx.x - nblk : blockIdx.x;
    const unsigned short* A = chain ? An : Ap;
    unsigned short*       G = chain ? Gn : Gp;
    int row0 = blk * 64;

    {
        int r  = tid >> 2;
        int c0 = (tid & 3) * 32;
        int gr = row0 + r;
        bool ok = gr < NN;
        const unsigned short* s = A + (size_t)(ok ? gr : 0) * C + c0;
        #pragma unroll
        for (int g = 0; g < 4; ++g) {
            uint4 v = ok ? *(const uint4*)(s + g * 8) : make_uint4(0, 0, 0, 0);
            int k = c0 + g * 8;
            int byte = (r * 256 + k * 2) ^ ((r & 7) << 4);
            *(uint4*)((char*)Ah + byte) = v;
        }
    }

    bf16x8 bh[2][4], bl[2][4];
    #pragma unroll
    for (int cf = 0; cf < 2; ++cf) {
        int col = wv * 32 + cf * 16 + (lane & 15);
        #pragma unroll
        for (int kt = 0; kt < 4; ++kt) {
            int k = kt * 32 + (lane >> 4) * 8;
            bh[cf][kt] = *(const bf16x8*)(Bh + (size_t)col * C + k);
            bl[cf][kt] = *(const bf16x8*)(Bl + (size_t)col * C + k);
        }
    }

    __syncthreads();

    f32x4 zero = {0.f, 0.f, 0.f, 0.f};
    f32x4 acc[4][2];
    #pragma unroll
    for (int rf = 0; rf < 4; ++rf)
        #pragma unroll
        for (int cf = 0; cf < 2; ++cf) acc[rf][cf] = zero;

    #pragma unroll
    for (int rf = 0; rf < 4; ++rf) {
        int row = rf * 16 + (lane & 15);
        #pragma unroll
        for (int kt = 0; kt < 4; ++kt) {
            int k = kt * 32 + (lane >> 4) * 8;
            int byte = (row * 256 + k * 2) ^ ((row & 7) << 4);
            bf16x8 a = *(const bf16x8*)((const char*)Ah + byte);
            #pragma unroll
            for (int cf = 0; cf < 2; ++cf) {
                acc[rf][cf] = __builtin_amdgcn_mfma_f32_16x16x32_bf16(a, bh[cf][kt], acc[rf][cf], 0, 0, 0);
                acc[rf][cf] = __builtin_amdgcn_mfma_f32_16x16x32_bf16(a, bl[cf][kt], acc[rf][cf], 0, 0, 0);
            }
        }
    }

    #pragma unroll
    for (int cf = 0; cf < 2; ++cf) {
        int col = wv * 32 + cf * 16 + (lane & 15);
        #pragma unroll
        for (int rf = 0; rf < 4; ++rf) {
            #pragma unroll
            for (int q = 0; q < 4; ++q) {
                int row = row0 + rf * 16 + (lane >> 4) * 4 + q;
                if (row < NN) G[(size_t)row * C + col] = f2bf(acc[rf][cf][q]);
            }
        }
    }
}

// ---------------------------------------------------------------------------
// k_agg3: CHAIN-FUSED aggregation — both chains in one block (grid = nb).
// v6: inner loop in fixed fully-unrolled chunks of 4 edges/group; cap rounded
// up to 8-slot multiple, padded slots carry weight=0 (valid src) -> branch-
// free body, 8 independent gathers in flight per lane (was ~2 at 28 VGPR).
// ---------------------------------------------------------------------------

template<bool PERMN>
__global__ __launch_bounds__(256) void k_agg3(const unsigned short* __restrict__ Gp,
                                              const unsigned short* __restrict__ Gn,
                                              const int* __restrict__ perm,
                                              const float* __restrict__ dinv,
                                              const unsigned* __restrict__ off,
                                              const uint2* __restrict__ em,
                                              const float* __restrict__ bias,
                                              const float* __restrict__ prelu,
                                              unsigned short* planeP, unsigned short* planeN,
                                              float* fP, float* fN) {
    __shared__ uint2 sem[4][64];
    int tid  = threadIdx.x;
    int lane = tid & 63;
    int wid  = tid >> 6;
    int half = lane >> 5;
    int gg   = (lane >> 4) & 1;
    int il   = lane & 15;
    int l32  = lane & 31;
    int i    = ((int)blockIdx.x * 4 + wid) * 2 + half;
    bool act = i < NN;
    const uint4* HP = (const uint4*)Gp;
    const uint4* HN = (const uint4*)Gn;

    float ap[8], an[8];
    {
        int ii = act ? i : 0;
        int sp = ii;
        int sn_ = PERMN ? perm[ii] : ii;
        uint4 hp = HP[(size_t)sp * 16 + il];
        uint4 hn = HN[(size_t)sn_ * 16 + il];
        float dv = act ? dinv[i] : 0.f;
        float sc = (gg == 0) ? dv * dv : 0.f;
        ap[0] = __uint_as_float(hp.x << 16) * sc;
        ap[1] = __uint_as_float(hp.x & 0xffff0000u) * sc;
        ap[2] = __uint_as_float(hp.y << 16) * sc;
        ap[3] = __uint_as_float(hp.y & 0xffff0000u) * sc;
        ap[4] = __uint_as_float(hp.z << 16) * sc;
        ap[5] = __uint_as_float(hp.z & 0xffff0000u) * sc;
        ap[6] = __uint_as_float(hp.w << 16) * sc;
        ap[7] = __uint_as_float(hp.w & 0xffff0000u) * sc;
        an[0] = __uint_as_float(hn.x << 16) * sc;
        an[1] = __uint_as_float(hn.x & 0xffff0000u) * sc;
        an[2] = __uint_as_float(hn.y << 16) * sc;
        an[3] = __uint_as_float(hn.y & 0xffff0000u) * sc;
        an[4] = __uint_as_float(hn.z << 16) * sc;
        an[5] = __uint_as_float(hn.z & 0xffff0000u) * sc;
        an[6] = __uint_as_float(hn.w << 16) * sc;
        an[7] = __uint_as_float(hn.w & 0xffff0000u) * sc;
    }

    unsigned p0 = 0, p1 = 0;
    if (act) { p0 = off[i]; p1 = off[i + 1]; }
    for (unsigned base = p0; base < p1; base += 32) {
        unsigned rem = p1 - base;
        int cap  = rem < 32u ? (int)rem : 32;
        int capr = (cap + 7) & ~7;     // padded to 8-slot multiple (<=32)
        u64 ev = __builtin_nontemporal_load(
            (const u64*)(em + base + ((unsigned)l32 < rem ? (unsigned)l32 : 0u)));
        if ((unsigned)l32 >= rem) ev &= 0xffffffffull;   // zero weight, keep src
        sem[wid][half * 32 + l32] = make_uint2((unsigned)ev, (unsigned)(ev >> 32));
        for (int b2 = 0; b2 < capr; b2 += 8) {
            uint2  e[4];
            uint4  hp[4], hn[4];
            #pragma unroll
            for (int u = 0; u < 4; ++u) {
                e[u] = sem[wid][half * 32 + b2 + gg + 2 * u];
                unsigned sp  = e[u].x;
                unsigned sn_ = PERMN ? (unsigned)perm[e[u].x] : e[u].x;
                hp[u] = HP[(size_t)sp * 16 + il];
                hn[u] = HN[(size_t)sn_ * 16 + il];
            }
            #pragma unroll
            for (int u = 0; u < 4; ++u) {
                float wv = __uint_as_float(e[u].y);
                ap[0] += __uint_as_float(hp[u].x << 16) * wv;
                ap[1] += __uint_as_float(hp[u].x & 0xffff0000u) * wv;
                ap[2] += __uint_as_float(hp[u].y << 16) * wv;
                ap[3] += __uint_as_float(hp[u].y & 0xffff0000u) * wv;
                ap[4] += __uint_as_float(hp[u].z << 16) * wv;
                ap[5] += __uint_as_float(hp[u].z & 0xffff0000u) * wv;
                ap[6] += __uint_as_float(hp[u].w << 16) * wv;
                ap[7] += __uint_as_float(hp[u].w & 0xffff0000u) * wv;
                an[0] += __uint_as_float(hn[u].x << 16) * wv;
                an[1] += __uint_as_float(hn[u].x & 0xffff0000u) * wv;
                an[2] += __uint_as_float(hn[u].y << 16) * wv;
                an[3] += __uint_as_float(hn[u].y & 0xffff0000u) * wv;
                an[4] += __uint_as_float(hn[u].z << 16) * wv;
                an[5] += __uint_as_float(hn[u].z & 0xffff0000u) * wv;
                an[6] += __uint_as_float(hn[u].w << 16) * wv;
                an[7] += __uint_as_float(hn[u].w & 0xffff0000u) * wv;
            }
        }
    }

    #pragma unroll
    for (int j = 0; j < 8; ++j) {
        ap[j] += __shfl_xor(ap[j], 16, 64);
        an[j] += __shfl_xor(an[j], 16, 64);
    }

    {
        float bv[8];
        *(float4*)&bv[0] = *(const float4*)(bias + il * 8);
        *(float4*)&bv[4] = *(const float4*)(bias + il * 8 + 4);
        #pragma unroll
        for (int j = 0; j < 8; ++j) { ap[j] += bv[j]; an[j] += bv[j]; }
        if (prelu) {
            float pv[8];
            *(float4*)&pv[0] = *(const float4*)(prelu + il * 8);
            *(float4*)&pv[4] = *(const float4*)(prelu + il * 8 + 4);
            #pragma unroll
            for (int j = 0; j < 8; ++j) {
                ap[j] = (ap[j] >= 0.f) ? ap[j] : pv[j] * ap[j];
                an[j] = (an[j] >= 0.f) ? an[j] : pv[j] * an[j];
            }
        }
    }

    if (act) {
        if (gg == 0 && planeP) {
            u32x4 o = { (unsigned)f2bf(ap[0]) | ((unsigned)f2bf(ap[1]) << 16),
                        (unsigned)f2bf(ap[2]) | ((unsigned)f2bf(ap[3]) << 16),
                        (unsigned)f2bf(ap[4]) | ((unsigned)f2bf(ap[5]) << 16),
                        (unsigned)f2bf(ap[6]) | ((unsigned)f2bf(ap[7]) << 16) };
            __builtin_nontemporal_store(o, (u32x4*)((uint4*)planeP + (size_t)i * 16 + il));
        }
        if (gg == 1 && planeN) {
            u32x4 o = { (unsigned)f2bf(an[0]) | ((unsigned)f2bf(an[1]) << 16),
                        (unsigned)f2bf(an[2]) | ((unsigned)f2bf(an[3]) << 16),
                        (unsigned)f2bf(an[4]) | ((unsigned)f2bf(an[5]) << 16),
                        (unsigned)f2bf(an[6]) | ((unsigned)f2bf(an[7]) << 16) };
            __builtin_nontemporal_store(o, (u32x4*)((uint4*)planeN + (size_t)i * 16 + il));
        }
        if (fP) {
            f32x4 v0 = { ap[0], ap[1], ap[2], ap[3] };
            f32x4 v1 = { ap[4], ap[5], ap[6], ap[7] };
            if (gg == 0) __builtin_nontemporal_store(v0, (f32x4*)(fP + (size_t)i * C + il * 8));
            else         __builtin_nontemporal_store(v1, (f32x4*)(fP + (size_t)i * C + il * 8 + 4));
        }
        if (fN) {
            f32x4 v0 = { an[0], an[1], an[2], an[3] };
            f32x4 v1 = { an[4], an[5], an[6], an[7] };
            if (gg == 1) __builtin_nontemporal_store(v0, (f32x4*)(fN + (size_t)i * C + il * 8));
            else         __builtin_nontemporal_store(v1, (f32x4*)(fN + (size_t)i * C + il * 8 + 4));
        }
    }
}

// ---------------------------------------------------------------------------
// k_agg2: single-chain aggregation (decoder), v6 chunked-unroll gather.
// ---------------------------------------------------------------------------

__global__ __launch_bounds__(256) void k_agg2(const unsigned short* __restrict__ G,
                                              const float* __restrict__ dinv,
                                              const unsigned* __restrict__ off,
                                              const uint2* __restrict__ em,
                                              const float* __restrict__ bias,
                                              float* __restrict__ fo) {
    __shared__ uint2 sem[4][64];
    int tid  = threadIdx.x;
    int lane = tid & 63;
    int wid  = tid >> 6;
    int half = lane >> 5;
    int gg   = (lane >> 4) & 1;
    int il   = lane & 15;
    int l32  = lane & 31;
    int i    = ((int)blockIdx.x * 4 + wid) * 2 + half;
    bool act = i < NN;
    const uint4* H4 = (const uint4*)G;

    float a[8];
    {
        uint4 hv = H4[(size_t)(act ? i : 0) * 16 + il];
        float dv = act ? dinv[i] : 0.f;
        float sn = (gg == 0) ? dv * dv : 0.f;
        a[0] = __uint_as_float(hv.x << 16) * sn;
        a[1] = __uint_as_float(hv.x & 0xffff0000u) * sn;
        a[2] = __uint_as_float(hv.y << 16) * sn;
        a[3] = __uint_as_float(hv.y & 0xffff0000u) * sn;
        a[4] = __uint_as_float(hv.z << 16) * sn;
        a[5] = __uint_as_float(hv.z & 0xffff0000u) * sn;
        a[6] = __uint_as_float(hv.w << 16) * sn;
        a[7] = __uint_as_float(hv.w & 0xffff0000u) * sn;
    }

    unsigned p0 = 0, p1 = 0;
    if (act) { p0 = off[i]; p1 = off[i + 1]; }
    for (unsigned base = p0; base < p1; base += 32) {
        unsigned rem = p1 - base;
        int cap  = rem < 32u ? (int)rem : 32;
        int capr = (cap + 7) & ~7;
        u64 ev = __builtin_nontemporal_load(
            (const u64*)(em + base + ((unsigned)l32 < rem ? (unsigned)l32 : 0u)));
        if ((unsigned)l32 >= rem) ev &= 0xffffffffull;
        sem[wid][half * 32 + l32] = make_uint2((unsigned)ev, (unsigned)(ev >> 32));
        for (int b2 = 0; b2 < capr; b2 += 8) {
            uint2 e[4];
            uint4 hv[4];
            #pragma unroll
            for (int u = 0; u < 4; ++u) {
                e[u] = sem[wid][half * 32 + b2 + gg + 2 * u];
                hv[u] = H4[(size_t)e[u].x * 16 + il];
            }
            #pragma unroll
            for (int u = 0; u < 4; ++u) {
                float wv = __uint_as_float(e[u].y);
                a[0] += __uint_as_float(hv[u].x << 16) * wv;
                a[1] += __uint_as_float(hv[u].x & 0xffff0000u) * wv;
                a[2] += __uint_as_float(hv[u].y << 16) * wv;
                a[3] += __uint_as_float(hv[u].y & 0xffff0000u) * wv;
                a[4] += __uint_as_float(hv[u].z << 16) * wv;
                a[5] += __uint_as_float(hv[u].z & 0xffff0000u) * wv;
                a[6] += __uint_as_float(hv[u].w << 16) * wv;
                a[7] += __uint_as_float(hv[u].w & 0xffff0000u) * wv;
            }
        }
    }

    #pragma unroll
    for (int j = 0; j < 8; ++j)
        a[j] += __shfl_xor(a[j], 16, 64);

    {
        float bv[8];
        *(float4*)&bv[0] = *(const float4*)(bias + il * 8);
        *(float4*)&bv[4] = *(const float4*)(bias + il * 8 + 4);
        #pragma unroll
        for (int j = 0; j < 8; ++j) a[j] += bv[j];
    }

    if (act) {
        f32x4 v0 = { a[0], a[1], a[2], a[3] };
        f32x4 v1 = { a[4], a[5], a[6], a[7] };
        if (gg == 0) __builtin_nontemporal_store(v0, (f32x4*)(fo + (size_t)i * C + il * 8));
        else         __builtin_nontemporal_store(v1, (f32x4*)(fo + (size_t)i * C + il * 8 + 4));
    }
}

// ---------------------------------------------------------------------------
// summary = sigmoid(mean(pos_z, axis=0))
// ---------------------------------------------------------------------------

__global__ __launch_bounds__(256) void k_sum(const float* __restrict__ pos, float* sumbuf) {
    __shared__ float red[256];
    int t = threadIdx.x;
    int c = t & 127;
    int half = t >> 7;
    float acc = 0.f;
    for (int r = blockIdx.x * 2 + half; r < NN; r += gridDim.x * 2)
        acc += pos[(size_t)r * C + c];
    red[t] = acc;
    __syncthreads();
    if (half == 0) atomicAdd(&sumbuf[c], acc + red[t + 128]);
}

__global__ void k_summary(const float* sumbuf, float* out) {
    int t = threadIdx.x;
    if (t < C) {
        float m = sumbuf[t] * (1.0f / (float)NN);
        out[t] = 1.0f / (1.0f + expf(-m));
    }
}

// ---------------------------------------------------------------------------
// q: Student's-t soft assignment. 256 thr: 64 nodes, 4 threads/node.
// ---------------------------------------------------------------------------

__global__ __launch_bounds__(256) void k_q(const float* __restrict__ xo,
                                           const float* __restrict__ mu,
                                           float* __restrict__ qout) {
    __shared__ float sx[64][132];
    __shared__ float smu[KC][128];
    __shared__ float smun[KC];
    int tid = threadIdx.x;
    for (int idx = tid; idx < KC * 128; idx += 256)
        smu[idx >> 7][idx & 127] = mu[idx];
    __syncthreads();
    if (tid < KC) {
        float s = 0.f;
        #pragma unroll 4
        for (int j = 0; j < 128; ++j) { float m = smu[tid][j]; s += m * m; }
        smun[tid] = s;
    }
    int n0 = blockIdx.x * 64;
    for (int idx = tid; idx < 64 * 32; idx += 256) {
        int r = idx >> 5;
        int c = (idx & 31) * 4;
        int gr = n0 + r;
        float4 v = make_float4(0.f, 0.f, 0.f, 0.f);
        if (gr < NN) v = *(const float4*)(xo + (size_t)gr * C + c);
        *(float4*)&sx[r][c] = v;
    }
    __syncthreads();
    int lr = tid >> 2;
    int g  = tid & 3;
    int node = n0 + lr;
    if (node < NN) {
        float ss = 0.f;
        #pragma unroll 8
        for (int j = 0; j < 128; ++j) { float x = sx[lr][j]; ss += x * x; }
        float qv[5]; float qs = 0.f;
        #pragma unroll
        for (int kk = 0; kk < 5; ++kk) {
            int k = g * 5 + kk;
            float dot = 0.f;
            #pragma unroll 8
            for (int j = 0; j < 128; ++j) dot += sx[lr][j] * smu[k][j];
            float d = ss + smun[k] - 2.0f * dot;
            d = fmaxf(d, 0.f);
            float q = 1.0f / (1.0f + d * 5.0f + 1e-8f);
            q = powf(q, 1.2f) * 0.5f;
            qv[kk] = q; qs += q;
        }
        qs += __shfl_xor(qs, 1, 64);
        qs += __shfl_xor(qs, 2, 64);
        float inv = 1.0f / qs;
        #pragma unroll
        for (int kk = 0; kk < 5; ++kk)
            qout[(size_t)node * KC + g * 5 + kk] = qv[kk] * inv;
    }
}

// ---------------------------------------------------------------------------
// launch
// ---------------------------------------------------------------------------

extern "C" void kernel_launch(void* const* d_in, const int* in_sizes, int n_in,
                              void* d_out, int out_size, void* d_ws, size_t ws_size,
                              hipStream_t stream) {
    const float* x    = (const float*)d_in[0];
    const int*   ei   = (const int*)d_in[1];
    const float* ew   = (const float*)d_in[2];
    const int*   perm = (const int*)d_in[3];
    const float* W1 = (const float*)d_in[4];  const float* b1 = (const float*)d_in[5];
    const float* W2 = (const float*)d_in[6];  const float* b2 = (const float*)d_in[7];
    const float* W3 = (const float*)d_in[8];  const float* b3 = (const float*)d_in[9];
    const float* W4 = (const float*)d_in[10]; const float* b4 = (const float*)d_in[11];
    const float* prelu_a = (const float*)d_in[12];
    const float* Wc = (const float*)d_in[13]; const float* bc = (const float*)d_in[14];
    const float* mu = (const float*)d_in[15];

    float* out     = (float*)d_out;
    float* pos_z   = out;                          // [N,128]
    float* neg_z   = out + (size_t)NN * C;         // [N,128]
    float* summary = out + (size_t)2 * NN * C;     // [128]
    float* xout    = summary + C;                  // [N,128]
    float* qout    = xout + (size_t)NN * C;        // [N,20]

    // workspace carve (~71 MB)
    char* w = (char*)d_ws;
    auto carve = [&](size_t bytes) { void* p = (void*)w; w += (bytes + 511) & ~(size_t)511; return p; };
    float*          dinv   = (float*)carve((size_t)NN * 4);
    unsigned*       cnt    = (unsigned*)carve((size_t)(NN + 1) * 4);  // -> off in place
    unsigned*       cursor = (unsigned*)carve((size_t)NN * 4);
    unsigned*       bsum   = (unsigned*)carve(256 * 4);
    unsigned*       total  = (unsigned*)carve(64);
    uint2*          em     = (uint2*)carve((size_t)EE * 8);           // (src, w)
    float*          sumbuf = (float*)carve(512);
    unsigned short* wt     = (unsigned short*)carve((size_t)5 * 2 * C * C * 2);
    unsigned short* Gp     = (unsigned short*)carve((size_t)NN * C * 2);
    unsigned short* Gn     = (unsigned short*)carve((size_t)NN * C * 2);
    unsigned short* P0     = (unsigned short*)carve((size_t)NN * C * 2);
    unsigned short* P1     = (unsigned short*)carve((size_t)NN * C * 2);
    unsigned short* P2     = (unsigned short*)carve((size_t)NN * C * 2);

    unsigned short* Wh[5], *Wl[5];
    for (int m = 0; m < 5; ++m) {
        Wh[m] = wt + (size_t)(2 * m) * C * C;
        Wl[m] = wt + (size_t)(2 * m + 1) * C * C;
    }

    hipMemsetAsync(cnt, 0, (size_t)(NN + 1) * 4, stream);
    hipMemsetAsync(sumbuf, 0, 512, stream);

    int gE = (EE + 255) / 256, gN = (NN + 255) / 256;
    int gM = (NN + 63) / 64;      // 782 blocks per chain (mm)
    int gA = (NN + 7) / 8;        // 6250 blocks (agg: 8 nodes/block, both chains)

    // weight split first (needed by the fused hist+mm launch)
    k_wsplit<<<320, 256, 0, stream>>>(W1, W2, W3, W4, Wc, wt);

    // fused: dst histogram + layer-1 GEMM (G1 = x@W1, shared by pos & neg)
    k_hist_mm<<<gE + gM, 256, 0, stream>>>(ei, cnt, x, Wh[0], Wl[0], Gp, gE);

    // scan + CSR fill + normalization
    k_scan1<<<NB, 256, 0, stream>>>(cnt, bsum);
    k_scan2<<<1, 64, 0, stream>>>(bsum, total);
    k_scan3<<<NB, 256, 0, stream>>>(cnt, bsum, total, cnt, cursor);   // cnt := off
    k_fill <<<gE, 256, 0, stream>>>(ei, ew, cursor, em);
    k_dinv_csr<<<gN, 256, 0, stream>>>(cnt, em, dinv);
    k_scale<<<gN, 256, 0, stream>>>(cnt, dinv, em);

    // Layer 1 (fused chains; (xW1)[perm] == (x[perm])W1 -> neg gathers via perm)
    k_agg3<true><<<gA, 256, 0, stream>>>(Gp, Gp, perm, dinv, cnt, em, b1, nullptr,
                                         P0, P1, nullptr, nullptr);
    // Layers 2-3
    k_mm2 <<<2 * gM, 256, 0, stream>>>(P0, P1, Wh[1], Wl[1], Gp, Gn, gM);
    k_agg3<false><<<gA, 256, 0, stream>>>(Gp, Gn, nullptr, dinv, cnt, em, b2, nullptr,
                                          P0, P1, nullptr, nullptr);
    k_mm2 <<<2 * gM, 256, 0, stream>>>(P0, P1, Wh[2], Wl[2], Gp, Gn, gM);
    k_agg3<false><<<gA, 256, 0, stream>>>(Gp, Gn, nullptr, dinv, cnt, em, b3, nullptr,
                                          P0, P1, nullptr, nullptr);
    // Layer 4 (PReLU; pos -> pos_z f32 + P2 plane, neg -> neg_z f32)
    k_mm2 <<<2 * gM, 256, 0, stream>>>(P0, P1, Wh[3], Wl[3], Gp, Gn, gM);
    k_agg3<false><<<gA, 256, 0, stream>>>(Gp, Gn, nullptr, dinv, cnt, em, b4, prelu_a,
                                          P2, nullptr, pos_z, neg_z);
    // Decoder: xout = Â(pos_z@Wc) + bc
    k_mm2 <<<gM, 256, 0, stream>>>(P2, P2, Wh[4], Wl[4], Gp, Gn, gM);
    k_agg2<<<gA, 256, 0, stream>>>(Gp, dinv, cnt, em, bc, xout);

    // summary
    k_sum<<<256, 256, 0, stream>>>(pos_z, sumbuf);
    k_summary<<<1, 128, 0, stream>>>(sumbuf, summary);

    // q soft assignment
    k_q<<<(NN + 63) / 64, 256, 0, stream>>>(xout, mu, qout);
}

// Round 14
// 584.919 us; speedup vs baseline: 1.0172x; 1.0172x over previous
//
#include <hip/hip_runtime.h>
#include <hip/hip_bf16.h>

// Problem constants (from reference)
constexpr int NN = 50000;   // nodes
constexpr int EE = 800000;  // edges
constexpr int C  = 128;     // channels (IN == H == 128)
constexpr int KC = 20;      // clusters
constexpr int NB = (NN + 1023) / 1024;   // scan blocks (49)

typedef __attribute__((ext_vector_type(8))) short bf16x8;   // 8 bf16 (4 VGPRs)
typedef __attribute__((ext_vector_type(4))) float f32x4;
typedef __attribute__((ext_vector_type(4))) unsigned int u32x4;
typedef unsigned long long u64;

__device__ inline unsigned short f2bf(float f) {            // RN f32->bf16
    unsigned u = __float_as_uint(f);
    u += 0x7fff + ((u >> 16) & 1);
    return (unsigned short)(u >> 16);
}
__device__ inline float bf2f(unsigned short h) {
    return __uint_as_float(((unsigned)h) << 16);
}

// ---------------------------------------------------------------------------
// Graph preprocessing (int inputs are int32 on device)
// ---------------------------------------------------------------------------

__global__ __launch_bounds__(256) void k_scan1(const unsigned* __restrict__ cnt,
                                               unsigned* __restrict__ bsum) {
    __shared__ unsigned red[256];
    int b = blockIdx.x, t = threadIdx.x;
    int i0 = b * 1024 + t * 4;
    unsigned s = 0;
    #pragma unroll
    for (int j = 0; j < 4; ++j) { int i = i0 + j; s += (i < NN) ? cnt[i] : 0u; }
    red[t] = s; __syncthreads();
    for (int st = 128; st > 0; st >>= 1) { if (t < st) red[t] += red[t + st]; __syncthreads(); }
    if (t == 0) bsum[b] = red[0];
}

__global__ void k_scan2(unsigned* bsum, unsigned* total) {   // 1 block, 64 thr
    int t = threadIdx.x;
    unsigned v = (t < NB) ? bsum[t] : 0u;
    unsigned x = v;
    #pragma unroll
    for (int s = 1; s < 64; s <<= 1) { unsigned u = __shfl_up(x, s, 64); if (t >= s) x += u; }
    if (t < NB) bsum[t] = x - v;     // exclusive block offset
    if (t == 63) *total = x;
}

__global__ __launch_bounds__(256) void k_scan3(const unsigned* __restrict__ cnt,
                                               const unsigned* __restrict__ bsum,
                                               const unsigned* __restrict__ total,
                                               unsigned* __restrict__ off,
                                               unsigned* __restrict__ cursor) {
    __shared__ unsigned wred[4];
    int b = blockIdx.x, t = threadIdx.x, lane = t & 63, wv = t >> 6;
    int i0 = b * 1024 + t * 4;
    unsigned v[4]; unsigned s = 0;
    #pragma unroll
    for (int j = 0; j < 4; ++j) { int i = i0 + j; v[j] = (i < NN) ? cnt[i] : 0u; s += v[j]; }
    unsigned x = s;
    #pragma unroll
    for (int st = 1; st < 64; st <<= 1) { unsigned u = __shfl_up(x, st, 64); if (lane >= st) x += u; }
    if (lane == 63) wred[wv] = x;
    __syncthreads();
    unsigned woff = 0;
    for (int k = 0; k < 4; ++k) if (k < wv) woff += wred[k];
    unsigned excl = bsum[b] + woff + x - s;
    #pragma unroll
    for (int j = 0; j < 4; ++j) {
        int i = i0 + j;
        if (i < NN) { off[i] = excl; cursor[i] = excl; excl += v[j]; }
    }
    if (b == 0 && t == 0) off[NN] = *total;
}

// CSR fill: plain cached loads + cached scatter store (round-7 behavior)
__global__ void k_fill(const int* __restrict__ ei, const float* __restrict__ ew,
                       unsigned* cursor, uint2* __restrict__ em) {
    int e = blockIdx.x * 256 + threadIdx.x;
    if (e >= EE) return;
    int s = ei[e];
    int d = ei[EE + e];
    unsigned p = atomicAdd(&cursor[d], 1u);
    em[p] = make_uint2((unsigned)s, __float_as_uint(ew[e]));
}

// deg[i] = 1 + sum(raw weights of row i); dinv = rsqrt
__global__ void k_dinv_csr(const unsigned* __restrict__ off,
                           const uint2* __restrict__ em, float* __restrict__ dinv) {
    int i = blockIdx.x * 256 + threadIdx.x;
    if (i >= NN) return;
    unsigned p0 = off[i], p1 = off[i + 1];
    float s = 1.0f;                       // self-loop weight
    for (unsigned p = p0; p < p1; ++p) s += __uint_as_float(em[p].y);
    dinv[i] = (s > 0.f) ? rsqrtf(s) : 0.f;
}

// em[p].w *= dinv[src]*dinv[dst]
__global__ void k_scale(const unsigned* __restrict__ off, const float* __restrict__ dinv,
                        uint2* __restrict__ em) {
    int i = blockIdx.x * 256 + threadIdx.x;
    if (i >= NN) return;
    float di = dinv[i];
    unsigned p0 = off[i], p1 = off[i + 1];
    for (unsigned p = p0; p < p1; ++p) {
        uint2 e = em[p];
        em[p].y = __float_as_uint(dinv[e.x] * __uint_as_float(e.y) * di);
    }
}

// ---------------------------------------------------------------------------
// Weight preconversion: 5 mats W[128][128] f32 -> Wt_hi/lo[col][k] bf16 (W^T)
// ---------------------------------------------------------------------------

__global__ void k_wsplit(const float* W0, const float* W1, const float* W2,
                         const float* W3, const float* W4,
                         unsigned short* __restrict__ wt) {
    int m = blockIdx.x >> 6;
    const float* W = (m == 0) ? W0 : (m == 1) ? W1 : (m == 2) ? W2 : (m == 3) ? W3 : W4;
    int idx = (blockIdx.x & 63) * 256 + threadIdx.x;   // 0..16383
    int k = idx >> 7, j = idx & 127;
    float v = W[idx];
    unsigned short h = f2bf(v);
    unsigned short* hi = wt + (size_t)(2 * m) * C * C;
    unsigned short* lo = wt + (size_t)(2 * m + 1) * C * C;
    hi[j * C + k] = h;
    lo[j * C + k] = f2bf(v - bf2f(h));
}

// ---------------------------------------------------------------------------
// k_hist_mm: fused launch. Blocks [0,histBlocks): dst histogram (atomic-bound,
// ~0.3% VALU -> hides the GEMM). Blocks [histBlocks,...): layer-1 GEMM
// G = x @ W1 (f32 A, 3-term hi/lo split) -> row-major bf16 plane.
// ---------------------------------------------------------------------------

__global__ __launch_bounds__(256) void k_hist_mm(const int* __restrict__ ei,
                                                 unsigned* cnt,
                                                 const float* __restrict__ A,
                                                 const unsigned short* __restrict__ Bh,
                                                 const unsigned short* __restrict__ Bl,
                                                 unsigned short* __restrict__ G,
                                                 int histBlocks) {
    int tid = threadIdx.x;
    if (blockIdx.x < histBlocks) {
        int e = blockIdx.x * 256 + tid;
        if (e < EE) atomicAdd(&cnt[__builtin_nontemporal_load(ei + EE + e)], 1u);
        return;
    }
    // ---- mm_f32 part ----
    __shared__ unsigned short Ah[64 * 128];
    __shared__ unsigned short Al[64 * 128];
    int lane = tid & 63;
    int wv   = tid >> 6;
    int row0 = (blockIdx.x - histBlocks) * 64;

    {
        int r  = tid >> 2;                 // 0..63
        int c0 = (tid & 3) * 32;
        int gr = row0 + r;
        bool ok = gr < NN;
        const float* src = A + (size_t)(ok ? gr : 0) * C + c0;
        #pragma unroll
        for (int g = 0; g < 4; ++g) {
            float f[8];
            if (ok) {
                *(float4*)&f[0] = *(const float4*)(src + g * 8);
                *(float4*)&f[4] = *(const float4*)(src + g * 8 + 4);
            } else {
                #pragma unroll
                for (int j = 0; j < 8; ++j) f[j] = 0.f;
            }
            union { unsigned short u[8]; uint4 v; } ph, pl;
            #pragma unroll
            for (int j = 0; j < 8; ++j) {
                unsigned short h = f2bf(f[j]);
                ph.u[j] = h;
                pl.u[j] = f2bf(f[j] - bf2f(h));
            }
            int k = c0 + g * 8;
            int byte = (r * 256 + k * 2) ^ ((r & 7) << 4);
            *(uint4*)((char*)Ah + byte) = ph.v;
            *(uint4*)((char*)Al + byte) = pl.v;
        }
    }

    bf16x8 bh[2][4], bl[2][4];
    #pragma unroll
    for (int cf = 0; cf < 2; ++cf) {
        int col = wv * 32 + cf * 16 + (lane & 15);
        #pragma unroll
        for (int kt = 0; kt < 4; ++kt) {
            int k = kt * 32 + (lane >> 4) * 8;
            bh[cf][kt] = *(const bf16x8*)(Bh + (size_t)col * C + k);
            bl[cf][kt] = *(const bf16x8*)(Bl + (size_t)col * C + k);
        }
    }

    __syncthreads();

    f32x4 zero = {0.f, 0.f, 0.f, 0.f};
    f32x4 acc[4][2];
    #pragma unroll
    for (int rf = 0; rf < 4; ++rf)
        #pragma unroll
        for (int cf = 0; cf < 2; ++cf) acc[rf][cf] = zero;

    #pragma unroll
    for (int rf = 0; rf < 4; ++rf) {
        int row = rf * 16 + (lane & 15);
        #pragma unroll
        for (int kt = 0; kt < 4; ++kt) {
            int k = kt * 32 + (lane >> 4) * 8;
            int byte = (row * 256 + k * 2) ^ ((row & 7) << 4);
            bf16x8 ah = *(const bf16x8*)((const char*)Ah + byte);
            bf16x8 al = *(const bf16x8*)((const char*)Al + byte);
            #pragma unroll
            for (int cf = 0; cf < 2; ++cf) {
                acc[rf][cf] = __builtin_amdgcn_mfma_f32_16x16x32_bf16(ah, bh[cf][kt], acc[rf][cf], 0, 0, 0);
                acc[rf][cf] = __builtin_amdgcn_mfma_f32_16x16x32_bf16(al, bh[cf][kt], acc[rf][cf], 0, 0, 0);
                acc[rf][cf] = __builtin_amdgcn_mfma_f32_16x16x32_bf16(ah, bl[cf][kt], acc[rf][cf], 0, 0, 0);
            }
        }
    }

    #pragma unroll
    for (int cf = 0; cf < 2; ++cf) {
        int col = wv * 32 + cf * 16 + (lane & 15);
        #pragma unroll
        for (int rf = 0; rf < 4; ++rf) {
            #pragma unroll
            for (int q = 0; q < 4; ++q) {
                int row = row0 + rf * 16 + (lane >> 4) * 4 + q;
                if (row < NN) G[(size_t)row * C + col] = f2bf(acc[rf][cf][q]);
            }
        }
    }
}

// ---------------------------------------------------------------------------
// k_mm2: G = A @ W for one or two chains (A bf16 plane exact -> 2-term MFMA).
// grid = nblk (single) or 2*nblk (dual: blockIdx>=nblk -> chain 1).
// ---------------------------------------------------------------------------

__global__ __launch_bounds__(256) void k_mm2(const unsigned short* __restrict__ Ap,
                                             const unsigned short* __restrict__ An,
                                             const unsigned short* __restrict__ Bh,
                                             const unsigned short* __restrict__ Bl,
                                             unsigned short* __restrict__ Gp,
                                             unsigned short* __restrict__ Gn, int nblk) {
    __shared__ unsigned short Ah[64 * 128];
    int tid  = threadIdx.x;
    int lane = tid & 63;
    int wv   = tid >> 6;
    int chain = blockIdx.x >= nblk;
    int blk   = chain ? blockIdx.x - nblk : blockIdx.x;
    const unsigned short* A = chain ? An : Ap;
    unsigned short*       G = chain ? Gn : Gp;
    int row0 = blk * 64;

    {
        int r  = tid >> 2;
        int c0 = (tid & 3) * 32;
        int gr = row0 + r;
        bool ok = gr < NN;
        const unsigned short* s = A + (size_t)(ok ? gr : 0) * C + c0;
        #pragma unroll
        for (int g = 0; g < 4; ++g) {
            uint4 v = ok ? *(const uint4*)(s + g * 8) : make_uint4(0, 0, 0, 0);
            int k = c0 + g * 8;
            int byte = (r * 256 + k * 2) ^ ((r & 7) << 4);
            *(uint4*)((char*)Ah + byte) = v;
        }
    }

    bf16x8 bh[2][4], bl[2][4];
    #pragma unroll
    for (int cf = 0; cf < 2; ++cf) {
        int col = wv * 32 + cf * 16 + (lane & 15);
        #pragma unroll
        for (int kt = 0; kt < 4; ++kt) {
            int k = kt * 32 + (lane >> 4) * 8;
            bh[cf][kt] = *(const bf16x8*)(Bh + (size_t)col * C + k);
            bl[cf][kt] = *(const bf16x8*)(Bl + (size_t)col * C + k);
        }
    }

    __syncthreads();

    f32x4 zero = {0.f, 0.f, 0.f, 0.f};
    f32x4 acc[4][2];
    #pragma unroll
    for (int rf = 0; rf < 4; ++rf)
        #pragma unroll
        for (int cf = 0; cf < 2; ++cf) acc[rf][cf] = zero;

    #pragma unroll
    for (int rf = 0; rf < 4; ++rf) {
        int row = rf * 16 + (lane & 15);
        #pragma unroll
        for (int kt = 0; kt < 4; ++kt) {
            int k = kt * 32 + (lane >> 4) * 8;
            int byte = (row * 256 + k * 2) ^ ((row & 7) << 4);
            bf16x8 a = *(const bf16x8*)((const char*)Ah + byte);
            #pragma unroll
            for (int cf = 0; cf < 2; ++cf) {
                acc[rf][cf] = __builtin_amdgcn_mfma_f32_16x16x32_bf16(a, bh[cf][kt], acc[rf][cf], 0, 0, 0);
                acc[rf][cf] = __builtin_amdgcn_mfma_f32_16x16x32_bf16(a, bl[cf][kt], acc[rf][cf], 0, 0, 0);
            }
        }
    }

    #pragma unroll
    for (int cf = 0; cf < 2; ++cf) {
        int col = wv * 32 + cf * 16 + (lane & 15);
        #pragma unroll
        for (int rf = 0; rf < 4; ++rf) {
            #pragma unroll
            for (int q = 0; q < 4; ++q) {
                int row = row0 + rf * 16 + (lane >> 4) * 4 + q;
                if (row < NN) G[(size_t)row * C + col] = f2bf(acc[rf][cf][q]);
            }
        }
    }
}

// ---------------------------------------------------------------------------
// k_agg3: CHAIN-FUSED aggregation — both chains in one block (grid = nb).
// Round-12 version (simple loop, 28 VGPR, best measured agg). Each staged
// edge feeds TWO independent gathers (Gp + Gn); per-node overhead amortized.
// PERMN: chain-1 (neg) applies perm to self+src (layer 1, Gn==Gp).
// ---------------------------------------------------------------------------

template<bool PERMN>
__global__ __launch_bounds__(256) void k_agg3(const unsigned short* __restrict__ Gp,
                                              const unsigned short* __restrict__ Gn,
                                              const int* __restrict__ perm,
                                              const float* __restrict__ dinv,
                                              const unsigned* __restrict__ off,
                                              const uint2* __restrict__ em,
                                              const float* __restrict__ bias,
                                              const float* __restrict__ prelu,
                                              unsigned short* planeP, unsigned short* planeN,
                                              float* fP, float* fN) {
    __shared__ uint2 sem[4][64];
    int tid  = threadIdx.x;
    int lane = tid & 63;
    int wid  = tid >> 6;
    int half = lane >> 5;
    int gg   = (lane >> 4) & 1;
    int il   = lane & 15;
    int l32  = lane & 31;
    int i    = ((int)blockIdx.x * 4 + wid) * 2 + half;
    bool act = i < NN;
    const uint4* HP = (const uint4*)Gp;
    const uint4* HN = (const uint4*)Gn;

    float ap[8], an[8];
    {
        int ii = act ? i : 0;
        int sp = ii;
        int sn_ = PERMN ? perm[ii] : ii;
        uint4 hp = HP[(size_t)sp * 16 + il];
        uint4 hn = HN[(size_t)sn_ * 16 + il];
        float dv = act ? dinv[i] : 0.f;
        float sc = (gg == 0) ? dv * dv : 0.f;
        ap[0] = __uint_as_float(hp.x << 16) * sc;
        ap[1] = __uint_as_float(hp.x & 0xffff0000u) * sc;
        ap[2] = __uint_as_float(hp.y << 16) * sc;
        ap[3] = __uint_as_float(hp.y & 0xffff0000u) * sc;
        ap[4] = __uint_as_float(hp.z << 16) * sc;
        ap[5] = __uint_as_float(hp.z & 0xffff0000u) * sc;
        ap[6] = __uint_as_float(hp.w << 16) * sc;
        ap[7] = __uint_as_float(hp.w & 0xffff0000u) * sc;
        an[0] = __uint_as_float(hn.x << 16) * sc;
        an[1] = __uint_as_float(hn.x & 0xffff0000u) * sc;
        an[2] = __uint_as_float(hn.y << 16) * sc;
        an[3] = __uint_as_float(hn.y & 0xffff0000u) * sc;
        an[4] = __uint_as_float(hn.z << 16) * sc;
        an[5] = __uint_as_float(hn.z & 0xffff0000u) * sc;
        an[6] = __uint_as_float(hn.w << 16) * sc;
        an[7] = __uint_as_float(hn.w & 0xffff0000u) * sc;
    }

    unsigned p0 = 0, p1 = 0;
    if (act) { p0 = off[i]; p1 = off[i + 1]; }
    for (unsigned base = p0; base < p1; base += 32) {
        unsigned rem = p1 - base;
        int cap = rem < 32u ? (int)rem : 32;
        u64 ev = __builtin_nontemporal_load(
            (const u64*)(em + base + ((unsigned)l32 < rem ? (unsigned)l32 : 0u)));
        sem[wid][half * 32 + l32] = make_uint2((unsigned)ev, (unsigned)(ev >> 32));
        #pragma unroll 4
        for (int t = gg; t < cap; t += 2) {
            uint2 e = sem[wid][half * 32 + t];
            unsigned sp = e.x;
            unsigned sn_ = PERMN ? (unsigned)perm[e.x] : e.x;
            float wv = __uint_as_float(e.y);
            uint4 hp = HP[(size_t)sp * 16 + il];
            uint4 hn = HN[(size_t)sn_ * 16 + il];
            ap[0] += __uint_as_float(hp.x << 16) * wv;
            ap[1] += __uint_as_float(hp.x & 0xffff0000u) * wv;
            ap[2] += __uint_as_float(hp.y << 16) * wv;
            ap[3] += __uint_as_float(hp.y & 0xffff0000u) * wv;
            ap[4] += __uint_as_float(hp.z << 16) * wv;
            ap[5] += __uint_as_float(hp.z & 0xffff0000u) * wv;
            ap[6] += __uint_as_float(hp.w << 16) * wv;
            ap[7] += __uint_as_float(hp.w & 0xffff0000u) * wv;
            an[0] += __uint_as_float(hn.x << 16) * wv;
            an[1] += __uint_as_float(hn.x & 0xffff0000u) * wv;
            an[2] += __uint_as_float(hn.y << 16) * wv;
            an[3] += __uint_as_float(hn.y & 0xffff0000u) * wv;
            an[4] += __uint_as_float(hn.z << 16) * wv;
            an[5] += __uint_as_float(hn.z & 0xffff0000u) * wv;
            an[6] += __uint_as_float(hn.w << 16) * wv;
            an[7] += __uint_as_float(hn.w & 0xffff0000u) * wv;
        }
    }

    #pragma unroll
    for (int j = 0; j < 8; ++j) {
        ap[j] += __shfl_xor(ap[j], 16, 64);
        an[j] += __shfl_xor(an[j], 16, 64);
    }

    {
        float bv[8];
        *(float4*)&bv[0] = *(const float4*)(bias + il * 8);
        *(float4*)&bv[4] = *(const float4*)(bias + il * 8 + 4);
        #pragma unroll
        for (int j = 0; j < 8; ++j) { ap[j] += bv[j]; an[j] += bv[j]; }
        if (prelu) {
            float pv[8];
            *(float4*)&pv[0] = *(const float4*)(prelu + il * 8);
            *(float4*)&pv[4] = *(const float4*)(prelu + il * 8 + 4);
            #pragma unroll
            for (int j = 0; j < 8; ++j) {
                ap[j] = (ap[j] >= 0.f) ? ap[j] : pv[j] * ap[j];
                an[j] = (an[j] >= 0.f) ? an[j] : pv[j] * an[j];
            }
        }
    }

    if (act) {
        if (gg == 0 && planeP) {
            u32x4 o = { (unsigned)f2bf(ap[0]) | ((unsigned)f2bf(ap[1]) << 16),
                        (unsigned)f2bf(ap[2]) | ((unsigned)f2bf(ap[3]) << 16),
                        (unsigned)f2bf(ap[4]) | ((unsigned)f2bf(ap[5]) << 16),
                        (unsigned)f2bf(ap[6]) | ((unsigned)f2bf(ap[7]) << 16) };
            __builtin_nontemporal_store(o, (u32x4*)((uint4*)planeP + (size_t)i * 16 + il));
        }
        if (gg == 1 && planeN) {
            u32x4 o = { (unsigned)f2bf(an[0]) | ((unsigned)f2bf(an[1]) << 16),
                        (unsigned)f2bf(an[2]) | ((unsigned)f2bf(an[3]) << 16),
                        (unsigned)f2bf(an[4]) | ((unsigned)f2bf(an[5]) << 16),
                        (unsigned)f2bf(an[6]) | ((unsigned)f2bf(an[7]) << 16) };
            __builtin_nontemporal_store(o, (u32x4*)((uint4*)planeN + (size_t)i * 16 + il));
        }
        if (fP) {
            f32x4 v0 = { ap[0], ap[1], ap[2], ap[3] };
            f32x4 v1 = { ap[4], ap[5], ap[6], ap[7] };
            if (gg == 0) __builtin_nontemporal_store(v0, (f32x4*)(fP + (size_t)i * C + il * 8));
            else         __builtin_nontemporal_store(v1, (f32x4*)(fP + (size_t)i * C + il * 8 + 4));
        }
        if (fN) {
            f32x4 v0 = { an[0], an[1], an[2], an[3] };
            f32x4 v1 = { an[4], an[5], an[6], an[7] };
            if (gg == 1) __builtin_nontemporal_store(v0, (f32x4*)(fN + (size_t)i * C + il * 8));
            else         __builtin_nontemporal_store(v1, (f32x4*)(fN + (size_t)i * C + il * 8 + 4));
        }
    }
}

// ---------------------------------------------------------------------------
// k_agg2: single-chain aggregation (decoder). Round-12 simple-loop version.
// ---------------------------------------------------------------------------

__global__ __launch_bounds__(256) void k_agg2(const unsigned short* __restrict__ G,
                                              const float* __restrict__ dinv,
                                              const unsigned* __restrict__ off,
                                              const uint2* __restrict__ em,
                                              const float* __restrict__ bias,
                                              float* __restrict__ fo) {
    __shared__ uint2 sem[4][64];
    int tid  = threadIdx.x;
    int lane = tid & 63;
    int wid  = tid >> 6;
    int half = lane >> 5;
    int gg   = (lane >> 4) & 1;
    int il   = lane & 15;
    int l32  = lane & 31;
    int i    = ((int)blockIdx.x * 4 + wid) * 2 + half;
    bool act = i < NN;
    const uint4* H4 = (const uint4*)G;

    float a[8];
    {
        uint4 hv = H4[(size_t)(act ? i : 0) * 16 + il];
        float dv = act ? dinv[i] : 0.f;
        float sn = (gg == 0) ? dv * dv : 0.f;
        a[0] = __uint_as_float(hv.x << 16) * sn;
        a[1] = __uint_as_float(hv.x & 0xffff0000u) * sn;
        a[2] = __uint_as_float(hv.y << 16) * sn;
        a[3] = __uint_as_float(hv.y & 0xffff0000u) * sn;
        a[4] = __uint_as_float(hv.z << 16) * sn;
        a[5] = __uint_as_float(hv.z & 0xffff0000u) * sn;
        a[6] = __uint_as_float(hv.w << 16) * sn;
        a[7] = __uint_as_float(hv.w & 0xffff0000u) * sn;
    }

    unsigned p0 = 0, p1 = 0;
    if (act) { p0 = off[i]; p1 = off[i + 1]; }
    for (unsigned base = p0; base < p1; base += 32) {
        unsigned rem = p1 - base;
        int cap = rem < 32u ? (int)rem : 32;
        u64 ev = __builtin_nontemporal_load(
            (const u64*)(em + base + ((unsigned)l32 < rem ? (unsigned)l32 : 0u)));
        sem[wid][half * 32 + l32] = make_uint2((unsigned)ev, (unsigned)(ev >> 32));
        #pragma unroll 4
        for (int t = gg; t < cap; t += 2) {
            uint2 e = sem[wid][half * 32 + t];
            float wv = __uint_as_float(e.y);
            uint4 hv = H4[(size_t)e.x * 16 + il];
            a[0] += __uint_as_float(hv.x << 16) * wv;
            a[1] += __uint_as_float(hv.x & 0xffff0000u) * wv;
            a[2] += __uint_as_float(hv.y << 16) * wv;
            a[3] += __uint_as_float(hv.y & 0xffff0000u) * wv;
            a[4] += __uint_as_float(hv.z << 16) * wv;
            a[5] += __uint_as_float(hv.z & 0xffff0000u) * wv;
            a[6] += __uint_as_float(hv.w << 16) * wv;
            a[7] += __uint_as_float(hv.w & 0xffff0000u) * wv;
        }
    }

    #pragma unroll
    for (int j = 0; j < 8; ++j)
        a[j] += __shfl_xor(a[j], 16, 64);

    {
        float bv[8];
        *(float4*)&bv[0] = *(const float4*)(bias + il * 8);
        *(float4*)&bv[4] = *(const float4*)(bias + il * 8 + 4);
        #pragma unroll
        for (int j = 0; j < 8; ++j) a[j] += bv[j];
    }

    if (act) {
        f32x4 v0 = { a[0], a[1], a[2], a[3] };
        f32x4 v1 = { a[4], a[5], a[6], a[7] };
        if (gg == 0) __builtin_nontemporal_store(v0, (f32x4*)(fo + (size_t)i * C + il * 8));
        else         __builtin_nontemporal_store(v1, (f32x4*)(fo + (size_t)i * C + il * 8 + 4));
    }
}

// ---------------------------------------------------------------------------
// summary = sigmoid(mean(pos_z, axis=0))
// ---------------------------------------------------------------------------

__global__ __launch_bounds__(256) void k_sum(const float* __restrict__ pos, float* sumbuf) {
    __shared__ float red[256];
    int t = threadIdx.x;
    int c = t & 127;
    int half = t >> 7;
    float acc = 0.f;
    for (int r = blockIdx.x * 2 + half; r < NN; r += gridDim.x * 2)
        acc += pos[(size_t)r * C + c];
    red[t] = acc;
    __syncthreads();
    if (half == 0) atomicAdd(&sumbuf[c], acc + red[t + 128]);
}

__global__ void k_summary(const float* sumbuf, float* out) {
    int t = threadIdx.x;
    if (t < C) {
        float m = sumbuf[t] * (1.0f / (float)NN);
        out[t] = 1.0f / (1.0f + expf(-m));
    }
}

// ---------------------------------------------------------------------------
// q: Student's-t soft assignment. 256 thr: 64 nodes, 4 threads/node.
// ---------------------------------------------------------------------------

__global__ __launch_bounds__(256) void k_q(const float* __restrict__ xo,
                                           const float* __restrict__ mu,
                                           float* __restrict__ qout) {
    __shared__ float sx[64][132];
    __shared__ float smu[KC][128];
    __shared__ float smun[KC];
    int tid = threadIdx.x;
    for (int idx = tid; idx < KC * 128; idx += 256)
        smu[idx >> 7][idx & 127] = mu[idx];
    __syncthreads();
    if (tid < KC) {
        float s = 0.f;
        #pragma unroll 4
        for (int j = 0; j < 128; ++j) { float m = smu[tid][j]; s += m * m; }
        smun[tid] = s;
    }
    int n0 = blockIdx.x * 64;
    for (int idx = tid; idx < 64 * 32; idx += 256) {
        int r = idx >> 5;
        int c = (idx & 31) * 4;
        int gr = n0 + r;
        float4 v = make_float4(0.f, 0.f, 0.f, 0.f);
        if (gr < NN) v = *(const float4*)(xo + (size_t)gr * C + c);
        *(float4*)&sx[r][c] = v;
    }
    __syncthreads();
    int lr = tid >> 2;
    int g  = tid & 3;
    int node = n0 + lr;
    if (node < NN) {
        float ss = 0.f;
        #pragma unroll 8
        for (int j = 0; j < 128; ++j) { float x = sx[lr][j]; ss += x * x; }
        float qv[5]; float qs = 0.f;
        #pragma unroll
        for (int kk = 0; kk < 5; ++kk) {
            int k = g * 5 + kk;
            float dot = 0.f;
            #pragma unroll 8
            for (int j = 0; j < 128; ++j) dot += sx[lr][j] * smu[k][j];
            float d = ss + smun[k] - 2.0f * dot;
            d = fmaxf(d, 0.f);
            float q = 1.0f / (1.0f + d * 5.0f + 1e-8f);
            q = powf(q, 1.2f) * 0.5f;
            qv[kk] = q; qs += q;
        }
        qs += __shfl_xor(qs, 1, 64);
        qs += __shfl_xor(qs, 2, 64);
        float inv = 1.0f / qs;
        #pragma unroll
        for (int kk = 0; kk < 5; ++kk)
            qout[(size_t)node * KC + g * 5 + kk] = qv[kk] * inv;
    }
}

// ---------------------------------------------------------------------------
// launch
// ---------------------------------------------------------------------------

extern "C" void kernel_launch(void* const* d_in, const int* in_sizes, int n_in,
                              void* d_out, int out_size, void* d_ws, size_t ws_size,
                              hipStream_t stream) {
    const float* x    = (const float*)d_in[0];
    const int*   ei   = (const int*)d_in[1];
    const float* ew   = (const float*)d_in[2];
    const int*   perm = (const int*)d_in[3];
    const float* W1 = (const float*)d_in[4];  const float* b1 = (const float*)d_in[5];
    const float* W2 = (const float*)d_in[6];  const float* b2 = (const float*)d_in[7];
    const float* W3 = (const float*)d_in[8];  const float* b3 = (const float*)d_in[9];
    const float* W4 = (const float*)d_in[10]; const float* b4 = (const float*)d_in[11];
    const float* prelu_a = (const float*)d_in[12];
    const float* Wc = (const float*)d_in[13]; const float* bc = (const float*)d_in[14];
    const float* mu = (const float*)d_in[15];

    float* out     = (float*)d_out;
    float* pos_z   = out;                          // [N,128]
    float* neg_z   = out + (size_t)NN * C;         // [N,128]
    float* summary = out + (size_t)2 * NN * C;     // [128]
    float* xout    = summary + C;                  // [N,128]
    float* qout    = xout + (size_t)NN * C;        // [N,20]

    // workspace carve (~71 MB)
    char* w = (char*)d_ws;
    auto carve = [&](size_t bytes) { void* p = (void*)w; w += (bytes + 511) & ~(size_t)511; return p; };
    float*          dinv   = (float*)carve((size_t)NN * 4);
    unsigned*       cnt    = (unsigned*)carve((size_t)(NN + 1) * 4);  // -> off in place
    unsigned*       cursor = (unsigned*)carve((size_t)NN * 4);
    unsigned*       bsum   = (unsigned*)carve(256 * 4);
    unsigned*       total  = (unsigned*)carve(64);
    uint2*          em     = (uint2*)carve((size_t)EE * 8);           // (src, w)
    float*          sumbuf = (float*)carve(512);
    unsigned short* wt     = (unsigned short*)carve((size_t)5 * 2 * C * C * 2);
    unsigned short* Gp     = (unsigned short*)carve((size_t)NN * C * 2);
    unsigned short* Gn     = (unsigned short*)carve((size_t)NN * C * 2);
    unsigned short* P0     = (unsigned short*)carve((size_t)NN * C * 2);
    unsigned short* P1     = (unsigned short*)carve((size_t)NN * C * 2);
    unsigned short* P2     = (unsigned short*)carve((size_t)NN * C * 2);

    unsigned short* Wh[5], *Wl[5];
    for (int m = 0; m < 5; ++m) {
        Wh[m] = wt + (size_t)(2 * m) * C * C;
        Wl[m] = wt + (size_t)(2 * m + 1) * C * C;
    }

    hipMemsetAsync(cnt, 0, (size_t)(NN + 1) * 4, stream);
    hipMemsetAsync(sumbuf, 0, 512, stream);

    int gE = (EE + 255) / 256, gN = (NN + 255) / 256;
    int gM = (NN + 63) / 64;      // 782 blocks per chain (mm)
    int gA = (NN + 7) / 8;        // 6250 blocks (agg: 8 nodes/block, both chains)

    // weight split first (needed by the fused hist+mm launch)
    k_wsplit<<<320, 256, 0, stream>>>(W1, W2, W3, W4, Wc, wt);

    // fused: dst histogram + layer-1 GEMM (G1 = x@W1, shared by pos & neg)
    k_hist_mm<<<gE + gM, 256, 0, stream>>>(ei, cnt, x, Wh[0], Wl[0], Gp, gE);

    // scan + CSR fill + normalization
    k_scan1<<<NB, 256, 0, stream>>>(cnt, bsum);
    k_scan2<<<1, 64, 0, stream>>>(bsum, total);
    k_scan3<<<NB, 256, 0, stream>>>(cnt, bsum, total, cnt, cursor);   // cnt := off
    k_fill <<<gE, 256, 0, stream>>>(ei, ew, cursor, em);
    k_dinv_csr<<<gN, 256, 0, stream>>>(cnt, em, dinv);
    k_scale<<<gN, 256, 0, stream>>>(cnt, dinv, em);

    // Layer 1 (fused chains; (xW1)[perm] == (x[perm])W1 -> neg gathers via perm)
    k_agg3<true><<<gA, 256, 0, stream>>>(Gp, Gp, perm, dinv, cnt, em, b1, nullptr,
                                         P0, P1, nullptr, nullptr);
    // Layers 2-3
    k_mm2 <<<2 * gM, 256, 0, stream>>>(P0, P1, Wh[1], Wl[1], Gp, Gn, gM);
    k_agg3<false><<<gA, 256, 0, stream>>>(Gp, Gn, nullptr, dinv, cnt, em, b2, nullptr,
                                          P0, P1, nullptr, nullptr);
    k_mm2 <<<2 * gM, 256, 0, stream>>>(P0, P1, Wh[2], Wl[2], Gp, Gn, gM);
    k_agg3<false><<<gA, 256, 0, stream>>>(Gp, Gn, nullptr, dinv, cnt, em, b3, nullptr,
                                          P0, P1, nullptr, nullptr);
    // Layer 4 (PReLU; pos -> pos_z f32 + P2 plane, neg -> neg_z f32)
    k_mm2 <<<2 * gM, 256, 0, stream>>>(P0, P1, Wh[3], Wl[3], Gp, Gn, gM);
    k_agg3<false><<<gA, 256, 0, stream>>>(Gp, Gn, nullptr, dinv, cnt, em, b4, prelu_a,
                                          P2, nullptr, pos_z, neg_z);
    // Decoder: xout = Â(pos_z@Wc) + bc
    k_mm2 <<<gM, 256, 0, stream>>>(P2, P2, Wh[4], Wl[4], Gp, Gn, gM);
    k_agg2<<<gA, 256, 0, stream>>>(Gp, dinv, cnt, em, bc, xout);

    // summary
    k_sum<<<256, 256, 0, stream>>>(pos_z, sumbuf);
    k_summary<<<1, 128, 0, stream>>>(sumbuf, summary);

    // q soft assignment
    k_q<<<(NN + 63) / 64, 256, 0, stream>>>(xout, mu, qout);
}